// Round 10
// baseline (164.115 us; speedup 1.0000x reference)
//
#include <hip/hip_runtime.h>
#include <hip/hip_bf16.h>
#include <stdint.h>

typedef __attribute__((ext_vector_type(8))) short short8;
typedef __attribute__((ext_vector_type(4))) unsigned int uint4v;
typedef __attribute__((ext_vector_type(4))) float floatx4;

#define W_DIM 900
#define NPAD  450
#define TM    256
#define TN    128
#define NT    32
#define BUFB  24576        // one LDS buffer: A 16 KB + B 8 KB

// packed fp32x2 -> bf16x2 (RNE). Standard HIP intrinsic so the compiler
// emits v_cvt_pk_bf16_f32 (1 inst / 2 values); the old bit-twiddle f2bf
// cost ~1.5 inst/value and dominated VALUBusy (r8: 20%).
// (__builtin_bit_cast rejects __hip_bfloat162 -- not trivially copyable in
// ROCm's header -- so use a 4-byte memcpy, which folds to a no-op.)
__device__ __forceinline__ unsigned int pkbf(float lo, float hi) {
  __hip_bfloat162 h = __float22bfloat162_rn(make_float2(lo, hi));
  unsigned int u;
  __builtin_memcpy(&u, &h, sizeof(u));
  return u;
}

__device__ __forceinline__ uint4v pk8(const float4& a, const float4& b) {
  uint4v o;
  o[0] = pkbf(a.x, a.y);
  o[1] = pkbf(a.z, a.w);
  o[2] = pkbf(b.x, b.y);
  o[3] = pkbf(b.z, b.w);
  return o;
}

// Raw barrier: drain own LDS ops, then workgroup barrier. Global loads stay
// in flight across it (__syncthreads would add vmcnt(0) and kill prefetch).
#define BARRIER() do { asm volatile("s_waitcnt lgkmcnt(0)" ::: "memory"); \
                       __builtin_amdgcn_s_barrier(); } while (0)

// ---------------------------------------------------------------------------
// Fused: fp32 inputs -> bf16 staged tiles -> gram GEMM -> circular-band reduce.
// out[b,s] = sum_{i-j-450 = s (mod 900)} <x1_i, x2_j>  (D = H*C = 1024)
//
// Round-10 = r9 resubmitted with the bit_cast -> memcpy compile fix:
// r8 base (66.9us: coalesced loads + swizzled-slot LDS [conflicts 0.33M]
// + dbuf 1-barrier/k-tile + unrolled clamped epilogue) + two changes:
//  (a) conversion via v_cvt_pk_bf16_f32 (HIP intrinsic, RNE) -- 4x fewer
//      VALU ops than the bit-twiddle round-half-up.
//  (b) s_setprio(1) around the MFMA cluster (T5): the 2 co-resident blocks
//      per CU are desynchronized, so priority arbitration has a target.
//
// LDS slot swizzle p = s ^ ((s>>3)&6): staging writes (lane -> row lane>>2,
// chunk lane&3) and frag reads (lane -> slot lane) both map bank-group
// bijectively per 8-lane group -> conflict-free b128 both ways.
//
// OOB tile rows (>=900) clamp their SOURCE POINTER to row 899 (in-bounds
// garbage); the epilogue k-range clamps exclude any gram entry with
// row>=900 or col>=900 from the band sums.
//
// Tile 256x128, BK=32. Grid 512, x = jt*64 + it*16 + b so x%8 = b%8 (XCD
// batch affinity). 4 waves; wave (wm,wn) = 128x64 via 8x4 frags 16x16x32bf16.
// Pipeline: iter t: BARRIER; frag-read buf[t&1]; CVTSTORE(t+1)->buf[~t]
// (vmcnt-waits loads(t+1)); issue LOADS(t+2); 32 MFMA.
// ---------------------------------------------------------------------------
__global__ __launch_bounds__(256, 2)
void fused_gram_band(const float* __restrict__ X1, const float* __restrict__ X2,
                     float* __restrict__ out) {
  const int x  = blockIdx.x;
  const int b  = x & 15;
  const int it = (x >> 4) & 3;         // A tile: rows it*256..
  const int jt = x >> 6;               // B tile: rows jt*128..

  __shared__ __align__(16) unsigned char smem[2 * BUFB];   // 49152 B
  // per buffer: A = 16 subtiles @ 0.., B = 8 subtiles @ 16384..; subtile =
  // (16 rows x 32 k) bf16 = 1024 B. Epilogue Ep[64][132] f32 (33792 B) aliases.

  const int tid  = threadIdx.x;
  const int lane = tid & 63;
  const int warp = tid >> 6;
  const int wm   = warp >> 1;
  const int wn   = warp & 1;
  const int r16  = lane & 15;
  const int quad = lane >> 4;

  // ---- staging lane map (coalesced): row-sub q = lane>>2, k8 chunk c.
  const int q  = lane >> 2;
  const int c  = lane & 3;
  const int c8 = c << 3;               // element offset within 32-elem k-tile

  // swizzled slot positions: p = s ^ ((s>>3)&6)
  const int pw = (((c << 4) | q) ^ (c << 1)) << 4;       // write: s=(c<<4)|q
  const int pr = (lane ^ ((lane >> 3) & 6)) << 4;        // read:  s=lane

  const size_t bbase = (size_t)b * 4 * W_DIM * 256;

  // row pointers, clamped to row 899 (garbage rows excluded in epilogue)
  const float* pA[4];
  const float* pB[2];
#pragma unroll
  for (int s = 0; s < 4; ++s) {
    int r = it * TM + (warp * 4 + s) * 16 + q;
    if (r > W_DIM - 1) r = W_DIM - 1;
    pA[s] = X1 + bbase + (size_t)r * 256 + c8;
  }
#pragma unroll
  for (int s = 0; s < 2; ++s) {
    int r = jt * TN + (warp * 2 + s) * 16 + q;
    if (r > W_DIM - 1) r = W_DIM - 1;
    pB[s] = X2 + bbase + (size_t)r * 256 + c8;
  }

  float4 va[4][2], vb[2][2];

#define LOAD_SLAB(kt)                                                          \
  {                                                                            \
    const size_t koff = (size_t)((kt) >> 3) * (W_DIM * 256) +                  \
                        ((kt) & 7) * 32;                                       \
    _Pragma("unroll")                                                          \
    for (int s = 0; s < 4; ++s) {                                              \
      va[s][0] = *(const float4*)(pA[s] + koff);                               \
      va[s][1] = *(const float4*)(pA[s] + koff + 4);                           \
    }                                                                          \
    _Pragma("unroll")                                                          \
    for (int s = 0; s < 2; ++s) {                                              \
      vb[s][0] = *(const float4*)(pB[s] + koff);                               \
      vb[s][1] = *(const float4*)(pB[s] + koff + 4);                           \
    }                                                                          \
  }

  // staging write bases (swizzled slots): subtile base + pw
  unsigned char* aWr = smem + warp * 4096 + pw;            // + s*1024 (+buf)
  unsigned char* bWr = smem + 16384 + warp * 2048 + pw;    // + s*1024 (+buf)

#define CVTSTORE(bo_)                                                          \
  {                                                                            \
    _Pragma("unroll")                                                          \
    for (int s = 0; s < 4; ++s)                                                \
      *(uint4v*)(aWr + (bo_) + s * 1024) = pk8(va[s][0], va[s][1]);            \
    _Pragma("unroll")                                                          \
    for (int s = 0; s < 2; ++s)                                                \
      *(uint4v*)(bWr + (bo_) + s * 1024) = pk8(vb[s][0], vb[s][1]);            \
  }

  floatx4 acc[8][4];
#pragma unroll
  for (int i = 0; i < 8; ++i)
#pragma unroll
    for (int j = 0; j < 4; ++j) acc[i][j] = (floatx4)0.0f;

  // frag read bases (swizzled slots): wave's subtile base + pr
  const unsigned char* aRd = smem + wm * 8192 + pr;           // + mi*1024 (+buf)
  const unsigned char* bRd = smem + 16384 + wn * 4096 + pr;   // + ni*1024 (+buf)

  LOAD_SLAB(0);
  CVTSTORE(0);           // vmcnt wait on loads(0) inserted here by compiler
  LOAD_SLAB(1);

  for (int t = 0; t < NT; ++t) {
    BARRIER();           // buf[t&1] stores visible; last iter's reads drained
    const int bo = (t & 1) * BUFB;

    short8 af[8], bf[4];
#pragma unroll
    for (int mi = 0; mi < 8; ++mi)
      af[mi] = *(const short8*)(aRd + bo + mi * 1024);
#pragma unroll
    for (int ni = 0; ni < 4; ++ni)
      bf[ni] = *(const short8*)(bRd + bo + ni * 1024);

    if (t < NT - 1) CVTSTORE((t + 1) & 1 ? BUFB : 0);  // consume loads(t+1)
    if (t < NT - 2) LOAD_SLAB(t + 2);                  // in flight over barrier

    __builtin_amdgcn_s_setprio(1);
#pragma unroll
    for (int mi = 0; mi < 8; ++mi)
#pragma unroll
      for (int ni = 0; ni < 4; ++ni)
        acc[mi][ni] = __builtin_amdgcn_mfma_f32_16x16x32_bf16(
            af[mi], bf[ni], acc[mi][ni], 0, 0, 0);
    __builtin_amdgcn_s_setprio(0);
  }

  // ---- Epilogue: gram[i,j] -> out[b, (i-j-450) mod 900]; 4 passes of 64 rows.
  __syncthreads();
  float* Ep = (float*)smem;            // [64][132]
  const int dbase = it * TM - jt * TN - NPAD;

  for (int p = 0; p < 4; ++p) {
    if (wm == (p >> 1)) {
      const int mib = (p & 1) * 4;
#pragma unroll
      for (int mo = 0; mo < 4; ++mo)
#pragma unroll
        for (int ni = 0; ni < 4; ++ni)
#pragma unroll
          for (int rr = 0; rr < 4; ++rr) {
            const int lr = mo * 16 + quad * 4 + rr;       // tile row p*64 + lr
            const int cc = wn * 64 + ni * 16 + r16;       // tile col
            Ep[lr * 132 + cc] = acc[mib + mo][ni][rr];
          }
    }
    __syncthreads();
    if (tid < 191) {
      const int d = tid - 127;         // lr - c in [-127, 63]
      int k0 = d > 0 ? d : 0;
      int k1 = 128 + d; if (k1 > 64) k1 = 64;
      // validity clamps (replaces hot-loop zero-fill): row it*256+p*64+k<900,
      // col jt*128+k-d<900
      {
        int kr = W_DIM - it * TM - p * 64;      // k < kr
        int kc = W_DIM + d - jt * TN;           // k < kc
        if (k1 > kr) k1 = kr;
        if (k1 > kc) k1 = kc;
      }
      if (k1 > k0) {
        float s0 = 0.f, s1 = 0.f, s2 = 0.f, s3 = 0.f;
        int k = k0;
        for (; k + 8 <= k1; k += 8) {
          s0 += Ep[(k + 0) * 133 - d];
          s1 += Ep[(k + 1) * 133 - d];
          s2 += Ep[(k + 2) * 133 - d];
          s3 += Ep[(k + 3) * 133 - d];
          s0 += Ep[(k + 4) * 133 - d];
          s1 += Ep[(k + 5) * 133 - d];
          s2 += Ep[(k + 6) * 133 - d];
          s3 += Ep[(k + 7) * 133 - d];
        }
        for (; k < k1; ++k) s0 += Ep[k * 133 - d];
        float s = (s0 + s1) + (s2 + s3);
        int dg = dbase + p * 64 + d;            // in (-1800, 1800)
        int sidx = dg % W_DIM;
        if (sidx < 0) sidx += W_DIM;
        atomicAdd(&out[b * W_DIM + sidx], s);
      }
    }
    __syncthreads();
  }
}

extern "C" void kernel_launch(void* const* d_in, const int* in_sizes, int n_in,
                              void* d_out, int out_size, void* d_ws, size_t ws_size,
                              hipStream_t stream) {
  const float* x1 = (const float*)d_in[0];
  const float* x2 = (const float*)d_in[1];
  float* out = (float*)d_out;

  (void)hipMemsetAsync(d_out, 0, (size_t)out_size * sizeof(float), stream);
  fused_gram_band<<<dim3(512), 256, 0, stream>>>(x1, x2, out);
}